// Round 5
// baseline (121.041 us; speedup 1.0000x reference)
//
#include <hip/hip_runtime.h>

#define NCAMS 5
#define BB 4
#define JJ 15
#define HH 128
#define WW 240
#define CXX 80
#define CYY 80
#define CZZ 20
#define NBINS 128000             // 80*80*20
#define HW (HH*WW)               // 30720
#define CUBES_ELEMS (BB*JJ*NBINS) // 7,680,000
#define BLOCK 256
#define BLOCKS_PER_B (NBINS / BLOCK) // 500
#define GRID (BB * BLOCKS_PER_B)     // 2000
#define WS_NEEDED ((size_t)NCAMS * BB * HW * 16)  // 9,830,400 B (u8 x16/pixel)

// ---- byte-permute / u8-dot helpers (compile-safe fallbacks) ---------------
__device__ __forceinline__ unsigned prm(unsigned a, unsigned b, unsigned s) {
#if __has_builtin(__builtin_amdgcn_perm)
    return __builtin_amdgcn_perm(a, b, s);
#else
    unsigned long long v = ((unsigned long long)a << 32) | b;
    unsigned r = 0;
#pragma unroll
    for (int i = 0; i < 4; ++i) {
        unsigned idx = (s >> (8 * i)) & 0xffu;
        unsigned byte = (idx < 8) ? (unsigned)((v >> (8 * idx)) & 0xff) : 0u;
        r |= byte << (8 * i);
    }
    return r;
#endif
}

__device__ __forceinline__ unsigned dot4u8(unsigned a, unsigned b, unsigned c) {
#if __has_builtin(__builtin_amdgcn_udot4)
    return __builtin_amdgcn_udot4(a, b, c, false);
#else
    return c + (a & 0xff) * (b & 0xff)
             + ((a >> 8) & 0xff) * ((b >> 8) & 0xff)
             + ((a >> 16) & 0xff) * ((b >> 16) & 0xff)
             + (a >> 24) * (b >> 24);
#endif
}

// ---------------------------------------------------------------------------
// Pass 1: transpose + u8 quantize (n,b,j,h,w) f32 -> (n,b,h,w,16) u8 (x255).
// One thread per pixel: 15 lane-coalesced 4B reads (nontemporal: no reuse),
// one 16B write (stays in L2 for pass 2).
// ---------------------------------------------------------------------------
__global__ __launch_bounds__(BLOCK) void transpose_kernel_u8(
    const float* __restrict__ hm, uint4* __restrict__ tz)
{
    const int t = blockIdx.x * BLOCK + threadIdx.x;   // < 5*4*HW = 614,400
    const int nb = t / HW;
    const int pix = t - nb * HW;
    const float* src = hm + (size_t)nb * JJ * HW + pix;
    unsigned w[4] = {0u, 0u, 0u, 0u};
#pragma unroll
    for (int j = 0; j < JJ; ++j) {
        const float v = __builtin_nontemporal_load(src + j * HW);
        unsigned u = (unsigned)(v * 255.f + 0.5f);
        u = u > 255u ? 255u : u;
        w[j >> 2] |= u << ((j & 3) * 8);
    }
    uint4 o; o.x = w[0]; o.y = w[1]; o.z = w[2]; o.w = w[3];
    tz[t] = o;
}

// ---------------------------------------------------------------------------
// Pass 2: projection + bilinear gather from u8 layout. BRANCHLESS camera
// loop: all 20 corner loads always issue (clamped indices are always valid);
// out-of-bounds cams contribute zero via wp=0. This removes divergence and
// lets the compiler pipeline loads across all 5 cameras (max MLP).
// Per dword-group (4 joints): 8-perm 4x4 byte transpose + 4 dot4_u32_u8.
// Output stores are nontemporal (36.9 MB streaming; don't evict u8 tiles).
// ---------------------------------------------------------------------------
__global__ __launch_bounds__(BLOCK) void project_kernel_u8(
    const uint4* __restrict__ tz,   // (5,4,HW) x 16 bytes
    const float* __restrict__ R, const float* __restrict__ T,
    const float* __restrict__ f, const float* __restrict__ c,
    const float* __restrict__ k, const float* __restrict__ p,
    const float* __restrict__ wh,
    const float* __restrict__ gc, const float* __restrict__ gs,
    float* __restrict__ out)
{
    const int tile = ((blockIdx.x & 7) * (GRID / 8)) + (blockIdx.x >> 3);
    const int b = tile / BLOCKS_PER_B;
    const int m = (tile % BLOCKS_PER_B) * BLOCK + threadIdx.x;

    const int i   = m / (CYY * CZZ);
    const int rem = m - i * (CYY * CZZ);
    const int jy  = rem / CZZ;
    const int kz  = rem - jy * CZZ;

    const float gs0 = gs[0], gs1 = gs[1], gs2 = gs[2];
    const float gx = -0.5f * gs0 + (float)i  * (gs0 / (float)(CXX - 1)) + gc[b * 3 + 0];
    const float gy = -0.5f * gs1 + (float)jy * (gs1 / (float)(CYY - 1)) + gc[b * 3 + 1];
    const float gz = -0.5f * gs2 + (float)kz * (gs2 / (float)(CZZ - 1)) + gc[b * 3 + 2];

    float* gout = out + CUBES_ELEMS + ((size_t)b * NBINS + m) * 3;
    __builtin_nontemporal_store(gx, gout + 0);
    __builtin_nontemporal_store(gy, gout + 1);
    __builtin_nontemporal_store(gz, gout + 2);

    unsigned acc[16];
#pragma unroll
    for (int j = 0; j < 16; ++j) acc[j] = 0u;
    float den = 0.f;

#pragma unroll
    for (int n = 0; n < NCAMS; ++n) {
        const int pb = n * BB + b;                 // wave-uniform
        const float* Rp = R + pb * 9;

        const float dx = gx - T[pb * 3 + 0];
        const float dy = gy - T[pb * 3 + 1];
        const float dz = gz - T[pb * 3 + 2];

        const float xc = Rp[0] * dx + Rp[1] * dy + Rp[2] * dz;
        const float yc = Rp[3] * dx + Rp[4] * dy + Rp[5] * dz;
        const float zc = Rp[6] * dx + Rp[7] * dy + Rp[8] * dz;

        const float y0 = xc / zc;
        const float y1 = yc / zc;
        const float r2 = y0 * y0 + y1 * y1;

        const float k0 = k[pb * 3 + 0], k1 = k[pb * 3 + 1], k2 = k[pb * 3 + 2];
        const float radial = 1.f + k0 * r2 + k1 * r2 * r2 + k2 * r2 * r2 * r2;
        const float p0v = p[pb * 2 + 0], p1v = p[pb * 2 + 1];
        const float s = radial + p0v * y1 + p1v * y0;
        const float xy0 = y0 * s + r2 * p1v;
        const float xy1 = y1 * s + r2 * p0v;

        const float pixx = xy0 * f[pb * 2 + 0] + c[pb * 2 + 0];
        const float pixy = xy1 * f[pb * 2 + 1] + c[pb * 2 + 1];

        const float wv = wh[pb * 2 + 0], hv = wh[pb * 2 + 1];
        const bool inb = (pixx >= 0.f) & (pixy >= 0.f) & (pixx < wv) & (pixy < hv);
        den += inb ? 1.f : 0.f;

        const float maxwh = fmaxf(wv, hv);
        float pcx = fminf(fmaxf(pixx, -1.f), maxwh);
        float pcy = fminf(fmaxf(pixy, -1.f), maxwh);
        float nx = fminf(fmaxf(pcx / (wv - 1.f) * 2.f - 1.f, -1.1f), 1.1f);
        float ny = fminf(fmaxf(pcy / (hv - 1.f) * 2.f - 1.f, -1.1f), 1.1f);

        const float ix = (nx + 1.f) * 0.5f * (float)(WW - 1);
        const float iy = (ny + 1.f) * 0.5f * (float)(HH - 1);
        const float x0f = floorf(ix), y0f = floorf(iy);
        const float x1f = x0f + 1.f, y1f = y0f + 1.f;
        const float wx1 = ix - x0f, wx0 = 1.f - wx1;
        const float wy1 = iy - y0f, wy0 = 1.f - wy1;

        const float vx0 = (x0f >= 0.f && x0f < (float)WW) ? 1.f : 0.f;
        const float vx1 = (x1f >= 0.f && x1f < (float)WW) ? 1.f : 0.f;
        const float vy0 = (y0f >= 0.f && y0f < (float)HH) ? 1.f : 0.f;
        const float vy1 = (y1f >= 0.f && y1f < (float)HH) ? 1.f : 0.f;

        const float w00 = wx0 * wy0 * vx0 * vy0;
        const float w10 = wx1 * wy0 * vx1 * vy0;
        const float w01 = wx0 * wy1 * vx0 * vy1;
        const float w11 = wx1 * wy1 * vx1 * vy1;

        const int xi0 = min(max((int)x0f, 0), WW - 1);
        const int xi1 = min(max((int)x1f, 0), WW - 1);
        const int yi0 = min(max((int)y0f, 0), HH - 1);
        const int yi1 = min(max((int)y1f, 0), HH - 1);

        const uint4* img = tz + (size_t)pb * HW;
        // unconditional corner loads (indices always valid)
        const uint4 A  = img[yi0 * WW + xi0];
        const uint4 Bc = img[yi0 * WW + xi1];
        const uint4 Cc = img[yi1 * WW + xi0];
        const uint4 D  = img[yi1 * WW + xi1];

        // 8-bit weights packed {w00,w10,w01,w11}; zeroed when cam out of bounds
        const unsigned u00 = (unsigned)(w00 * 255.f + 0.5f);
        const unsigned u10 = (unsigned)(w10 * 255.f + 0.5f);
        const unsigned u01 = (unsigned)(w01 * 255.f + 0.5f);
        const unsigned u11 = (unsigned)(w11 * 255.f + 0.5f);
        unsigned wp = u00 | (u10 << 8) | (u01 << 16) | (u11 << 24);
        wp = inb ? wp : 0u;

        const unsigned Aa[4] = {A.x,  A.y,  A.z,  A.w};
        const unsigned Ba[4] = {Bc.x, Bc.y, Bc.z, Bc.w};
        const unsigned Ca[4] = {Cc.x, Cc.y, Cc.z, Cc.w};
        const unsigned Da[4] = {D.x,  D.y,  D.z,  D.w};

#pragma unroll
        for (int d = 0; d < 4; ++d) {
            // 4x4 byte transpose: {A,B,C,D}[d] -> r_j = {A_j,B_j,C_j,D_j}
            const unsigned tABlo = prm(Aa[d], Ba[d], 0x01050004u); // {A0,B0,A1,B1}
            const unsigned tABhi = prm(Aa[d], Ba[d], 0x03070206u); // {A2,B2,A3,B3}
            const unsigned tCDlo = prm(Ca[d], Da[d], 0x01050004u); // {C0,D0,C1,D1}
            const unsigned tCDhi = prm(Ca[d], Da[d], 0x03070206u); // {C2,D2,C3,D3}
            const unsigned r0 = prm(tABlo, tCDlo, 0x01000504u);    // {A0,B0,C0,D0}
            const unsigned r1 = prm(tABlo, tCDlo, 0x03020706u);    // {A1,B1,C1,D1}
            const unsigned r2 = prm(tABhi, tCDhi, 0x01000504u);
            const unsigned r3 = prm(tABhi, tCDhi, 0x03020706u);
            acc[4 * d + 0] = dot4u8(r0, wp, acc[4 * d + 0]);
            acc[4 * d + 1] = dot4u8(r1, wp, acc[4 * d + 1]);
            acc[4 * d + 2] = dot4u8(r2, wp, acc[4 * d + 2]);
            acc[4 * d + 3] = dot4u8(r3, wp, acc[4 * d + 3]);
        }
    }

    const float inv = 1.f / ((den + 1e-6f) * (255.f * 255.f));
    float* cout = out + (size_t)b * JJ * NBINS + m;
#pragma unroll
    for (int j = 0; j < JJ; ++j) {
        float v = (float)acc[j] * inv;
        v = fminf(fmaxf(v, 0.f), 1.f);
        __builtin_nontemporal_store(v, cout + (size_t)j * NBINS);
    }
}

// ---------------------------------------------------------------------------
// Fallback (R1 kernel): used only if ws_size < WS_NEEDED.
// ---------------------------------------------------------------------------
__global__ __launch_bounds__(BLOCK) void project_kernel_fb(
    const float* __restrict__ hm,
    const float* __restrict__ R, const float* __restrict__ T,
    const float* __restrict__ f, const float* __restrict__ c,
    const float* __restrict__ k, const float* __restrict__ p,
    const float* __restrict__ wh,
    const float* __restrict__ gc, const float* __restrict__ gs,
    float* __restrict__ out)
{
    const int b = blockIdx.x / BLOCKS_PER_B;
    const int m = (blockIdx.x % BLOCKS_PER_B) * BLOCK + threadIdx.x;
    const int i   = m / (CYY * CZZ);
    const int rem = m - i * (CYY * CZZ);
    const int jy  = rem / CZZ;
    const int kz  = rem - jy * CZZ;

    const float gs0 = gs[0], gs1 = gs[1], gs2 = gs[2];
    const float gx = -0.5f * gs0 + (float)i  * (gs0 / (float)(CXX - 1)) + gc[b * 3 + 0];
    const float gy = -0.5f * gs1 + (float)jy * (gs1 / (float)(CYY - 1)) + gc[b * 3 + 1];
    const float gz = -0.5f * gs2 + (float)kz * (gs2 / (float)(CZZ - 1)) + gc[b * 3 + 2];

    float* gout = out + CUBES_ELEMS + ((size_t)b * NBINS + m) * 3;
    gout[0] = gx; gout[1] = gy; gout[2] = gz;

    float num[JJ];
#pragma unroll
    for (int j = 0; j < JJ; ++j) num[j] = 0.f;
    float den = 0.f;

    for (int n = 0; n < NCAMS; ++n) {
        const int pb = n * BB + b;
        const float* Rp = R + pb * 9;
        const float dx = gx - T[pb * 3 + 0];
        const float dy = gy - T[pb * 3 + 1];
        const float dz = gz - T[pb * 3 + 2];
        const float xc = Rp[0] * dx + Rp[1] * dy + Rp[2] * dz;
        const float yc = Rp[3] * dx + Rp[4] * dy + Rp[5] * dz;
        const float zc = Rp[6] * dx + Rp[7] * dy + Rp[8] * dz;
        const float y0 = xc / zc;
        const float y1 = yc / zc;
        const float r2 = y0 * y0 + y1 * y1;
        const float k0 = k[pb * 3 + 0], k1 = k[pb * 3 + 1], k2 = k[pb * 3 + 2];
        const float radial = 1.f + k0 * r2 + k1 * r2 * r2 + k2 * r2 * r2 * r2;
        const float p0v = p[pb * 2 + 0], p1v = p[pb * 2 + 1];
        const float s = radial + p0v * y1 + p1v * y0;
        const float xy0 = y0 * s + r2 * p1v;
        const float xy1 = y1 * s + r2 * p0v;
        const float pixx = xy0 * f[pb * 2 + 0] + c[pb * 2 + 0];
        const float pixy = xy1 * f[pb * 2 + 1] + c[pb * 2 + 1];
        const float wv = wh[pb * 2 + 0], hv = wh[pb * 2 + 1];
        const bool inb = (pixx >= 0.f) & (pixy >= 0.f) & (pixx < wv) & (pixy < hv);
        if (!inb) continue;
        den += 1.f;
        const float maxwh = fmaxf(wv, hv);
        float pcx = fminf(fmaxf(pixx, -1.f), maxwh);
        float pcy = fminf(fmaxf(pixy, -1.f), maxwh);
        float nx = fminf(fmaxf(pcx / (wv - 1.f) * 2.f - 1.f, -1.1f), 1.1f);
        float ny = fminf(fmaxf(pcy / (hv - 1.f) * 2.f - 1.f, -1.1f), 1.1f);
        const float ix = (nx + 1.f) * 0.5f * (float)(WW - 1);
        const float iy = (ny + 1.f) * 0.5f * (float)(HH - 1);
        const float x0f = floorf(ix), y0f = floorf(iy);
        const float x1f = x0f + 1.f, y1f = y0f + 1.f;
        const float wx1 = ix - x0f, wx0 = 1.f - wx1;
        const float wy1 = iy - y0f, wy0 = 1.f - wy1;
        const float vx0 = (x0f >= 0.f && x0f < (float)WW) ? 1.f : 0.f;
        const float vx1 = (x1f >= 0.f && x1f < (float)WW) ? 1.f : 0.f;
        const float vy0 = (y0f >= 0.f && y0f < (float)HH) ? 1.f : 0.f;
        const float vy1 = (y1f >= 0.f && y1f < (float)HH) ? 1.f : 0.f;
        const float w00 = wx0 * wy0 * vx0 * vy0;
        const float w10 = wx1 * wy0 * vx1 * vy0;
        const float w01 = wx0 * wy1 * vx0 * vy1;
        const float w11 = wx1 * wy1 * vx1 * vy1;
        const int xi0 = min(max((int)x0f, 0), WW - 1);
        const int xi1 = min(max((int)x1f, 0), WW - 1);
        const int yi0 = min(max((int)y0f, 0), HH - 1);
        const int yi1 = min(max((int)y1f, 0), HH - 1);
        const int o00 = yi0 * WW + xi0;
        const int o10 = yi0 * WW + xi1;
        const int o01 = yi1 * WW + xi0;
        const int o11 = yi1 * WW + xi1;
        const float* img = hm + (size_t)pb * JJ * HW;
#pragma unroll
        for (int j = 0; j < JJ; ++j) {
            const float* pj = img + j * HW;
            num[j] += pj[o00] * w00 + pj[o10] * w10 + pj[o01] * w01 + pj[o11] * w11;
        }
    }

    const float inv = 1.f / (den + 1e-6f);
    float* cout = out + (size_t)b * JJ * NBINS + m;
#pragma unroll
    for (int j = 0; j < JJ; ++j) {
        float v = num[j] * inv;
        v = (v != v) ? 0.f : v;
        v = fminf(fmaxf(v, 0.f), 1.f);
        cout[(size_t)j * NBINS] = v;
    }
}

extern "C" void kernel_launch(void* const* d_in, const int* in_sizes, int n_in,
                              void* d_out, int out_size, void* d_ws, size_t ws_size,
                              hipStream_t stream) {
    const float* hm = (const float*)d_in[0];
    const float* R  = (const float*)d_in[1];
    const float* T  = (const float*)d_in[2];
    const float* f  = (const float*)d_in[3];
    const float* c  = (const float*)d_in[4];
    const float* k  = (const float*)d_in[5];
    const float* p  = (const float*)d_in[6];
    const float* wh = (const float*)d_in[7];
    const float* gc = (const float*)d_in[8];
    const float* gs = (const float*)d_in[9];
    float* out = (float*)d_out;

    if (ws_size >= WS_NEEDED) {
        uint4* tz = (uint4*)d_ws;
        transpose_kernel_u8<<<dim3(NCAMS * BB * HW / BLOCK), dim3(BLOCK), 0, stream>>>(
            hm, tz);
        project_kernel_u8<<<dim3(GRID), dim3(BLOCK), 0, stream>>>(
            tz, R, T, f, c, k, p, wh, gc, gs, out);
    } else {
        project_kernel_fb<<<dim3(GRID), dim3(BLOCK), 0, stream>>>(
            hm, R, T, f, c, k, p, wh, gc, gs, out);
    }
}

// Round 6
// 119.479 us; speedup vs baseline: 1.0131x; 1.0131x over previous
//
#include <hip/hip_runtime.h>

#define NCAMS 5
#define BB 4
#define JJ 15
#define HH 128
#define WW 240
#define CXX 80
#define CYY 80
#define CZZ 20
#define NBINS 128000             // 80*80*20
#define HW (HH*WW)               // 30720
#define CUBES_ELEMS (BB*JJ*NBINS) // 7,680,000
#define BLOCK 256
#define BLOCKS_PER_B (NBINS / BLOCK) // 500
#define GRID (BB * BLOCKS_PER_B)     // 2000
#define WS_NEEDED ((size_t)NCAMS * BB * HW * 16)  // 9,830,400 B (u8 x16/pixel)

// ---- byte-permute / u8-dot / rcp helpers (compile-safe fallbacks) ---------
__device__ __forceinline__ unsigned prm(unsigned a, unsigned b, unsigned s) {
#if __has_builtin(__builtin_amdgcn_perm)
    return __builtin_amdgcn_perm(a, b, s);
#else
    unsigned long long v = ((unsigned long long)a << 32) | b;
    unsigned r = 0;
#pragma unroll
    for (int i = 0; i < 4; ++i) {
        unsigned idx = (s >> (8 * i)) & 0xffu;
        unsigned byte = (idx < 8) ? (unsigned)((v >> (8 * idx)) & 0xff) : 0u;
        r |= byte << (8 * i);
    }
    return r;
#endif
}

__device__ __forceinline__ unsigned dot4u8(unsigned a, unsigned b, unsigned c) {
#if __has_builtin(__builtin_amdgcn_udot4)
    return __builtin_amdgcn_udot4(a, b, c, false);
#else
    return c + (a & 0xff) * (b & 0xff)
             + ((a >> 8) & 0xff) * ((b >> 8) & 0xff)
             + ((a >> 16) & 0xff) * ((b >> 16) & 0xff)
             + (a >> 24) * (b >> 24);
#endif
}

__device__ __forceinline__ float frcp(float x) {
#if __has_builtin(__builtin_amdgcn_rcpf)
    return __builtin_amdgcn_rcpf(x);   // v_rcp_f32, ~1 ulp — fine at our tolerance
#else
    return 1.f / x;
#endif
}

// ---------------------------------------------------------------------------
// Pass 1: transpose + u8 quantize (n,b,j,h,w) f32 -> (n,b,h,w,16) u8 (x255).
// ---------------------------------------------------------------------------
__global__ __launch_bounds__(BLOCK) void transpose_kernel_u8(
    const float* __restrict__ hm, uint4* __restrict__ tz)
{
    const int t = blockIdx.x * BLOCK + threadIdx.x;   // < 5*4*HW = 614,400
    const int nb = t / HW;
    const int pix = t - nb * HW;
    const float* src = hm + (size_t)nb * JJ * HW + pix;
    unsigned w[4] = {0u, 0u, 0u, 0u};
#pragma unroll
    for (int j = 0; j < JJ; ++j) {
        const float v = __builtin_nontemporal_load(src + j * HW);
        unsigned u = (unsigned)(v * 255.f + 0.5f);
        u = u > 255u ? 255u : u;
        w[j >> 2] |= u << ((j & 3) * 8);
    }
    uint4 o; o.x = w[0]; o.y = w[1]; o.z = w[2]; o.w = w[3];
    tz[t] = o;
}

// ---------------------------------------------------------------------------
// Pass 2: two-stage pipeline. Stage 1: ALL 5 cameras' projection math and
// ALL 20 corner loads issued into registers (no consumption -> single vmcnt
// drain per thread instead of five). Stage 2: byte-transpose + dot4 blend.
// Divides replaced with v_rcp_f32. Branchless (wp=0 for OOB cams).
// ---------------------------------------------------------------------------
__global__ __launch_bounds__(BLOCK) void project_kernel_u8(
    const uint4* __restrict__ tz,   // (5,4,HW) x 16 bytes
    const float* __restrict__ R, const float* __restrict__ T,
    const float* __restrict__ f, const float* __restrict__ c,
    const float* __restrict__ k, const float* __restrict__ p,
    const float* __restrict__ wh,
    const float* __restrict__ gc, const float* __restrict__ gs,
    float* __restrict__ out)
{
    const int tile = ((blockIdx.x & 7) * (GRID / 8)) + (blockIdx.x >> 3);
    const int b = tile / BLOCKS_PER_B;
    const int m = (tile % BLOCKS_PER_B) * BLOCK + threadIdx.x;

    const int i   = m / (CYY * CZZ);
    const int rem = m - i * (CYY * CZZ);
    const int jy  = rem / CZZ;
    const int kz  = rem - jy * CZZ;

    const float gs0 = gs[0], gs1 = gs[1], gs2 = gs[2];
    const float gx = -0.5f * gs0 + (float)i  * (gs0 / (float)(CXX - 1)) + gc[b * 3 + 0];
    const float gy = -0.5f * gs1 + (float)jy * (gs1 / (float)(CYY - 1)) + gc[b * 3 + 1];
    const float gz = -0.5f * gs2 + (float)kz * (gs2 / (float)(CZZ - 1)) + gc[b * 3 + 2];

    float* gout = out + CUBES_ELEMS + ((size_t)b * NBINS + m) * 3;
    __builtin_nontemporal_store(gx, gout + 0);
    __builtin_nontemporal_store(gy, gout + 1);
    __builtin_nontemporal_store(gz, gout + 2);

    // ---------------- stage 1: math + load issue for all cameras ----------
    uint4 LA[NCAMS], LB[NCAMS], LC[NCAMS], LD[NCAMS];
    unsigned wpk[NCAMS];
    float den = 0.f;

#pragma unroll
    for (int n = 0; n < NCAMS; ++n) {
        const int pb = n * BB + b;                 // wave-uniform
        const float* Rp = R + pb * 9;

        const float dx = gx - T[pb * 3 + 0];
        const float dy = gy - T[pb * 3 + 1];
        const float dz = gz - T[pb * 3 + 2];

        const float xc = Rp[0] * dx + Rp[1] * dy + Rp[2] * dz;
        const float yc = Rp[3] * dx + Rp[4] * dy + Rp[5] * dz;
        const float zc = Rp[6] * dx + Rp[7] * dy + Rp[8] * dz;

        const float rz = frcp(zc);
        const float y0 = xc * rz;
        const float y1 = yc * rz;
        const float r2 = y0 * y0 + y1 * y1;

        const float k0 = k[pb * 3 + 0], k1 = k[pb * 3 + 1], k2 = k[pb * 3 + 2];
        const float radial = 1.f + k0 * r2 + k1 * r2 * r2 + k2 * r2 * r2 * r2;
        const float p0v = p[pb * 2 + 0], p1v = p[pb * 2 + 1];
        const float s = radial + p0v * y1 + p1v * y0;
        const float xy0 = y0 * s + r2 * p1v;
        const float xy1 = y1 * s + r2 * p0v;

        const float pixx = xy0 * f[pb * 2 + 0] + c[pb * 2 + 0];
        const float pixy = xy1 * f[pb * 2 + 1] + c[pb * 2 + 1];

        const float wv = wh[pb * 2 + 0], hv = wh[pb * 2 + 1];
        const bool inb = (pixx >= 0.f) & (pixy >= 0.f) & (pixx < wv) & (pixy < hv);
        den += inb ? 1.f : 0.f;

        const float maxwh = fmaxf(wv, hv);
        float pcx = fminf(fmaxf(pixx, -1.f), maxwh);
        float pcy = fminf(fmaxf(pixy, -1.f), maxwh);
        float nx = fminf(fmaxf(pcx * frcp(wv - 1.f) * 2.f - 1.f, -1.1f), 1.1f);
        float ny = fminf(fmaxf(pcy * frcp(hv - 1.f) * 2.f - 1.f, -1.1f), 1.1f);

        const float ix = (nx + 1.f) * 0.5f * (float)(WW - 1);
        const float iy = (ny + 1.f) * 0.5f * (float)(HH - 1);
        const float x0f = floorf(ix), y0f = floorf(iy);
        const float x1f = x0f + 1.f, y1f = y0f + 1.f;
        const float wx1 = ix - x0f, wx0 = 1.f - wx1;
        const float wy1 = iy - y0f, wy0 = 1.f - wy1;

        const float vx0 = (x0f >= 0.f && x0f < (float)WW) ? 1.f : 0.f;
        const float vx1 = (x1f >= 0.f && x1f < (float)WW) ? 1.f : 0.f;
        const float vy0 = (y0f >= 0.f && y0f < (float)HH) ? 1.f : 0.f;
        const float vy1 = (y1f >= 0.f && y1f < (float)HH) ? 1.f : 0.f;

        const float w00 = wx0 * wy0 * vx0 * vy0;
        const float w10 = wx1 * wy0 * vx1 * vy0;
        const float w01 = wx0 * wy1 * vx0 * vy1;
        const float w11 = wx1 * wy1 * vx1 * vy1;

        const int xi0 = min(max((int)x0f, 0), WW - 1);
        const int xi1 = min(max((int)x1f, 0), WW - 1);
        const int yi0 = min(max((int)y0f, 0), HH - 1);
        const int yi1 = min(max((int)y1f, 0), HH - 1);

        const unsigned u00 = (unsigned)(w00 * 255.f + 0.5f);
        const unsigned u10 = (unsigned)(w10 * 255.f + 0.5f);
        const unsigned u01 = (unsigned)(w01 * 255.f + 0.5f);
        const unsigned u11 = (unsigned)(w11 * 255.f + 0.5f);
        unsigned wp = u00 | (u10 << 8) | (u01 << 16) | (u11 << 24);
        wpk[n] = inb ? wp : 0u;

        const uint4* img = tz + (size_t)pb * HW;
        LA[n] = img[yi0 * WW + xi0];
        LB[n] = img[yi0 * WW + xi1];
        LC[n] = img[yi1 * WW + xi0];
        LD[n] = img[yi1 * WW + xi1];
    }

    // ---------------- stage 2: blend all cameras --------------------------
    unsigned acc[16];
#pragma unroll
    for (int j = 0; j < 16; ++j) acc[j] = 0u;

#pragma unroll
    for (int n = 0; n < NCAMS; ++n) {
        const unsigned wp = wpk[n];
        const unsigned Aa[4] = {LA[n].x, LA[n].y, LA[n].z, LA[n].w};
        const unsigned Ba[4] = {LB[n].x, LB[n].y, LB[n].z, LB[n].w};
        const unsigned Ca[4] = {LC[n].x, LC[n].y, LC[n].z, LC[n].w};
        const unsigned Da[4] = {LD[n].x, LD[n].y, LD[n].z, LD[n].w};
#pragma unroll
        for (int d = 0; d < 4; ++d) {
            const unsigned tABlo = prm(Aa[d], Ba[d], 0x01050004u); // {A0,B0,A1,B1}
            const unsigned tABhi = prm(Aa[d], Ba[d], 0x03070206u); // {A2,B2,A3,B3}
            const unsigned tCDlo = prm(Ca[d], Da[d], 0x01050004u);
            const unsigned tCDhi = prm(Ca[d], Da[d], 0x03070206u);
            const unsigned r0 = prm(tABlo, tCDlo, 0x01000504u);    // {A0,B0,C0,D0}
            const unsigned r1 = prm(tABlo, tCDlo, 0x03020706u);
            const unsigned r2 = prm(tABhi, tCDhi, 0x01000504u);
            const unsigned r3 = prm(tABhi, tCDhi, 0x03020706u);
            acc[4 * d + 0] = dot4u8(r0, wp, acc[4 * d + 0]);
            acc[4 * d + 1] = dot4u8(r1, wp, acc[4 * d + 1]);
            acc[4 * d + 2] = dot4u8(r2, wp, acc[4 * d + 2]);
            acc[4 * d + 3] = dot4u8(r3, wp, acc[4 * d + 3]);
        }
    }

    const float inv = frcp((den + 1e-6f) * (255.f * 255.f));
    float* cout = out + (size_t)b * JJ * NBINS + m;
#pragma unroll
    for (int j = 0; j < JJ; ++j) {
        float v = (float)acc[j] * inv;
        v = fminf(fmaxf(v, 0.f), 1.f);
        __builtin_nontemporal_store(v, cout + (size_t)j * NBINS);
    }
}

// ---------------------------------------------------------------------------
// Fallback (R1 kernel): used only if ws_size < WS_NEEDED.
// ---------------------------------------------------------------------------
__global__ __launch_bounds__(BLOCK) void project_kernel_fb(
    const float* __restrict__ hm,
    const float* __restrict__ R, const float* __restrict__ T,
    const float* __restrict__ f, const float* __restrict__ c,
    const float* __restrict__ k, const float* __restrict__ p,
    const float* __restrict__ wh,
    const float* __restrict__ gc, const float* __restrict__ gs,
    float* __restrict__ out)
{
    const int b = blockIdx.x / BLOCKS_PER_B;
    const int m = (blockIdx.x % BLOCKS_PER_B) * BLOCK + threadIdx.x;
    const int i   = m / (CYY * CZZ);
    const int rem = m - i * (CYY * CZZ);
    const int jy  = rem / CZZ;
    const int kz  = rem - jy * CZZ;

    const float gs0 = gs[0], gs1 = gs[1], gs2 = gs[2];
    const float gx = -0.5f * gs0 + (float)i  * (gs0 / (float)(CXX - 1)) + gc[b * 3 + 0];
    const float gy = -0.5f * gs1 + (float)jy * (gs1 / (float)(CYY - 1)) + gc[b * 3 + 1];
    const float gz = -0.5f * gs2 + (float)kz * (gs2 / (float)(CZZ - 1)) + gc[b * 3 + 2];

    float* gout = out + CUBES_ELEMS + ((size_t)b * NBINS + m) * 3;
    gout[0] = gx; gout[1] = gy; gout[2] = gz;

    float num[JJ];
#pragma unroll
    for (int j = 0; j < JJ; ++j) num[j] = 0.f;
    float den = 0.f;

    for (int n = 0; n < NCAMS; ++n) {
        const int pb = n * BB + b;
        const float* Rp = R + pb * 9;
        const float dx = gx - T[pb * 3 + 0];
        const float dy = gy - T[pb * 3 + 1];
        const float dz = gz - T[pb * 3 + 2];
        const float xc = Rp[0] * dx + Rp[1] * dy + Rp[2] * dz;
        const float yc = Rp[3] * dx + Rp[4] * dy + Rp[5] * dz;
        const float zc = Rp[6] * dx + Rp[7] * dy + Rp[8] * dz;
        const float y0 = xc / zc;
        const float y1 = yc / zc;
        const float r2 = y0 * y0 + y1 * y1;
        const float k0 = k[pb * 3 + 0], k1 = k[pb * 3 + 1], k2 = k[pb * 3 + 2];
        const float radial = 1.f + k0 * r2 + k1 * r2 * r2 + k2 * r2 * r2 * r2;
        const float p0v = p[pb * 2 + 0], p1v = p[pb * 2 + 1];
        const float s = radial + p0v * y1 + p1v * y0;
        const float xy0 = y0 * s + r2 * p1v;
        const float xy1 = y1 * s + r2 * p0v;
        const float pixx = xy0 * f[pb * 2 + 0] + c[pb * 2 + 0];
        const float pixy = xy1 * f[pb * 2 + 1] + c[pb * 2 + 1];
        const float wv = wh[pb * 2 + 0], hv = wh[pb * 2 + 1];
        const bool inb = (pixx >= 0.f) & (pixy >= 0.f) & (pixx < wv) & (pixy < hv);
        if (!inb) continue;
        den += 1.f;
        const float maxwh = fmaxf(wv, hv);
        float pcx = fminf(fmaxf(pixx, -1.f), maxwh);
        float pcy = fminf(fmaxf(pixy, -1.f), maxwh);
        float nx = fminf(fmaxf(pcx / (wv - 1.f) * 2.f - 1.f, -1.1f), 1.1f);
        float ny = fminf(fmaxf(pcy / (hv - 1.f) * 2.f - 1.f, -1.1f), 1.1f);
        const float ix = (nx + 1.f) * 0.5f * (float)(WW - 1);
        const float iy = (ny + 1.f) * 0.5f * (float)(HH - 1);
        const float x0f = floorf(ix), y0f = floorf(iy);
        const float x1f = x0f + 1.f, y1f = y0f + 1.f;
        const float wx1 = ix - x0f, wx0 = 1.f - wx1;
        const float wy1 = iy - y0f, wy0 = 1.f - wy1;
        const float vx0 = (x0f >= 0.f && x0f < (float)WW) ? 1.f : 0.f;
        const float vx1 = (x1f >= 0.f && x1f < (float)WW) ? 1.f : 0.f;
        const float vy0 = (y0f >= 0.f && y0f < (float)HH) ? 1.f : 0.f;
        const float vy1 = (y1f >= 0.f && y1f < (float)HH) ? 1.f : 0.f;
        const float w00 = wx0 * wy0 * vx0 * vy0;
        const float w10 = wx1 * wy0 * vx1 * vy0;
        const float w01 = wx0 * wy1 * vx0 * vy1;
        const float w11 = wx1 * wy1 * vx1 * vy1;
        const int xi0 = min(max((int)x0f, 0), WW - 1);
        const int xi1 = min(max((int)x1f, 0), WW - 1);
        const int yi0 = min(max((int)y0f, 0), HH - 1);
        const int yi1 = min(max((int)y1f, 0), HH - 1);
        const int o00 = yi0 * WW + xi0;
        const int o10 = yi0 * WW + xi1;
        const int o01 = yi1 * WW + xi0;
        const int o11 = yi1 * WW + xi1;
        const float* img = hm + (size_t)pb * JJ * HW;
#pragma unroll
        for (int j = 0; j < JJ; ++j) {
            const float* pj = img + j * HW;
            num[j] += pj[o00] * w00 + pj[o10] * w10 + pj[o01] * w01 + pj[o11] * w11;
        }
    }

    const float inv = 1.f / (den + 1e-6f);
    float* cout = out + (size_t)b * JJ * NBINS + m;
#pragma unroll
    for (int j = 0; j < JJ; ++j) {
        float v = num[j] * inv;
        v = (v != v) ? 0.f : v;
        v = fminf(fmaxf(v, 0.f), 1.f);
        cout[(size_t)j * NBINS] = v;
    }
}

extern "C" void kernel_launch(void* const* d_in, const int* in_sizes, int n_in,
                              void* d_out, int out_size, void* d_ws, size_t ws_size,
                              hipStream_t stream) {
    const float* hm = (const float*)d_in[0];
    const float* R  = (const float*)d_in[1];
    const float* T  = (const float*)d_in[2];
    const float* f  = (const float*)d_in[3];
    const float* c  = (const float*)d_in[4];
    const float* k  = (const float*)d_in[5];
    const float* p  = (const float*)d_in[6];
    const float* wh = (const float*)d_in[7];
    const float* gc = (const float*)d_in[8];
    const float* gs = (const float*)d_in[9];
    float* out = (float*)d_out;

    if (ws_size >= WS_NEEDED) {
        uint4* tz = (uint4*)d_ws;
        transpose_kernel_u8<<<dim3(NCAMS * BB * HW / BLOCK), dim3(BLOCK), 0, stream>>>(
            hm, tz);
        project_kernel_u8<<<dim3(GRID), dim3(BLOCK), 0, stream>>>(
            tz, R, T, f, c, k, p, wh, gc, gs, out);
    } else {
        project_kernel_fb<<<dim3(GRID), dim3(BLOCK), 0, stream>>>(
            hm, R, T, f, c, k, p, wh, gc, gs, out);
    }
}

// Round 7
// 118.838 us; speedup vs baseline: 1.0185x; 1.0054x over previous
//
#include <hip/hip_runtime.h>

#define NCAMS 5
#define BB 4
#define JJ 15
#define HH 128
#define WW 240
#define CXX 80
#define CYY 80
#define CZZ 20
#define NBINS 128000             // 80*80*20
#define HW (HH*WW)               // 30720
#define CUBES_ELEMS (BB*JJ*NBINS) // 7,680,000
#define BLOCK 256
#define BLOCKS_PER_B (NBINS / BLOCK) // 500
#define GRID (BB * BLOCKS_PER_B)     // 2000
#define WS_NEEDED ((size_t)NCAMS * BB * HW * 8)   // 4,915,200 B (u4 x16 nibbles/pixel)

// unaligned-capable 16B vector (pixel pairs are only 8B-aligned)
typedef unsigned uint4a __attribute__((ext_vector_type(4), aligned(8)));

// ---- byte-permute / u8-dot / rcp helpers (compile-safe fallbacks) ---------
__device__ __forceinline__ unsigned prm(unsigned a, unsigned b, unsigned s) {
#if __has_builtin(__builtin_amdgcn_perm)
    return __builtin_amdgcn_perm(a, b, s);
#else
    unsigned long long v = ((unsigned long long)a << 32) | b;
    unsigned r = 0;
#pragma unroll
    for (int i = 0; i < 4; ++i) {
        unsigned idx = (s >> (8 * i)) & 0xffu;
        unsigned byte = (idx < 8) ? (unsigned)((v >> (8 * idx)) & 0xff) : 0u;
        r |= byte << (8 * i);
    }
    return r;
#endif
}

__device__ __forceinline__ unsigned dot4u8(unsigned a, unsigned b, unsigned c) {
#if __has_builtin(__builtin_amdgcn_udot4)
    return __builtin_amdgcn_udot4(a, b, c, false);
#else
    return c + (a & 0xff) * (b & 0xff)
             + ((a >> 8) & 0xff) * ((b >> 8) & 0xff)
             + ((a >> 16) & 0xff) * ((b >> 16) & 0xff)
             + (a >> 24) * (b >> 24);
#endif
}

__device__ __forceinline__ float frcp(float x) {
#if __has_builtin(__builtin_amdgcn_rcpf)
    return __builtin_amdgcn_rcpf(x);
#else
    return 1.f / x;
#endif
}

// ---------------------------------------------------------------------------
// Pass 1: transpose + u4 quantize (n,b,j,h,w) f32 -> (n,b,h,w) x 16 nibbles.
// Joint j lives at nibble (j&7) of dword (j>>3); value = round(v*15).
// One thread per pixel: 15 lane-coalesced reads, one 8B write.
// ---------------------------------------------------------------------------
__global__ __launch_bounds__(BLOCK) void transpose_kernel_u4(
    const float* __restrict__ hm, uint2* __restrict__ tz)
{
    const int t = blockIdx.x * BLOCK + threadIdx.x;   // < 5*4*HW = 614,400
    const int nb = t / HW;
    const int pix = t - nb * HW;
    const float* src = hm + (size_t)nb * JJ * HW + pix;
    unsigned d0 = 0u, d1 = 0u;
#pragma unroll
    for (int j = 0; j < JJ; ++j) {
        const float v = __builtin_nontemporal_load(src + j * HW);
        unsigned u = (unsigned)(v * 15.f + 0.5f);
        u = u > 15u ? 15u : u;
        if (j < 8) d0 |= u << (4 * j);
        else       d1 |= u << (4 * (j - 8));
    }
    uint2 o; o.x = d0; o.y = d1;
    tz[t] = o;
}

// ---------------------------------------------------------------------------
// Pass 2: projection + bilinear gather, u4 pixels. Per cam only TWO 16B
// loads: row y0 pixel-pair [xb,xb+1] and row y1 pair (x-corners contiguous).
// Slot-weight remap handles x-clamp edges exactly. Per 4-joint group:
// nibble-extract (AND/SHR) + 8-perm byte transpose + 4x dot4_u32_u8 with
// packed 8-bit slot weights {s0,s1,t0,t1}; i32 accumulate across cams.
// ---------------------------------------------------------------------------
__global__ __launch_bounds__(BLOCK) void project_kernel_u4(
    const unsigned char* __restrict__ tz,  // (5,4,HW) x 8 bytes
    const float* __restrict__ R, const float* __restrict__ T,
    const float* __restrict__ f, const float* __restrict__ c,
    const float* __restrict__ k, const float* __restrict__ p,
    const float* __restrict__ wh,
    const float* __restrict__ gc, const float* __restrict__ gs,
    float* __restrict__ out)
{
    const int tile = ((blockIdx.x & 7) * (GRID / 8)) + (blockIdx.x >> 3);
    const int b = tile / BLOCKS_PER_B;
    const int m = (tile % BLOCKS_PER_B) * BLOCK + threadIdx.x;

    const int i   = m / (CYY * CZZ);
    const int rem = m - i * (CYY * CZZ);
    const int jy  = rem / CZZ;
    const int kz  = rem - jy * CZZ;

    const float gs0 = gs[0], gs1 = gs[1], gs2 = gs[2];
    const float gx = -0.5f * gs0 + (float)i  * (gs0 / (float)(CXX - 1)) + gc[b * 3 + 0];
    const float gy = -0.5f * gs1 + (float)jy * (gs1 / (float)(CYY - 1)) + gc[b * 3 + 1];
    const float gz = -0.5f * gs2 + (float)kz * (gs2 / (float)(CZZ - 1)) + gc[b * 3 + 2];

    float* gout = out + CUBES_ELEMS + ((size_t)b * NBINS + m) * 3;
    __builtin_nontemporal_store(gx, gout + 0);
    __builtin_nontemporal_store(gy, gout + 1);
    __builtin_nontemporal_store(gz, gout + 2);

    // ---------------- stage 1: math + all 10 loads -------------------------
    uint4a L0[NCAMS], L1[NCAMS];
    unsigned wpk[NCAMS];
    float den = 0.f;

#pragma unroll
    for (int n = 0; n < NCAMS; ++n) {
        const int pb = n * BB + b;                 // wave-uniform
        const float* Rp = R + pb * 9;

        const float dx = gx - T[pb * 3 + 0];
        const float dy = gy - T[pb * 3 + 1];
        const float dz = gz - T[pb * 3 + 2];

        const float xc = Rp[0] * dx + Rp[1] * dy + Rp[2] * dz;
        const float yc = Rp[3] * dx + Rp[4] * dy + Rp[5] * dz;
        const float zc = Rp[6] * dx + Rp[7] * dy + Rp[8] * dz;

        const float rz = frcp(zc);
        const float y0 = xc * rz;
        const float y1 = yc * rz;
        const float r2 = y0 * y0 + y1 * y1;

        const float k0 = k[pb * 3 + 0], k1 = k[pb * 3 + 1], k2 = k[pb * 3 + 2];
        const float radial = 1.f + k0 * r2 + k1 * r2 * r2 + k2 * r2 * r2 * r2;
        const float p0v = p[pb * 2 + 0], p1v = p[pb * 2 + 1];
        const float s = radial + p0v * y1 + p1v * y0;
        const float xy0 = y0 * s + r2 * p1v;
        const float xy1 = y1 * s + r2 * p0v;

        const float pixx = xy0 * f[pb * 2 + 0] + c[pb * 2 + 0];
        const float pixy = xy1 * f[pb * 2 + 1] + c[pb * 2 + 1];

        const float wv = wh[pb * 2 + 0], hv = wh[pb * 2 + 1];
        const bool inb = (pixx >= 0.f) & (pixy >= 0.f) & (pixx < wv) & (pixy < hv);
        den += inb ? 1.f : 0.f;

        const float maxwh = fmaxf(wv, hv);
        float pcx = fminf(fmaxf(pixx, -1.f), maxwh);
        float pcy = fminf(fmaxf(pixy, -1.f), maxwh);
        float nx = fminf(fmaxf(pcx * frcp(wv - 1.f) * 2.f - 1.f, -1.1f), 1.1f);
        float ny = fminf(fmaxf(pcy * frcp(hv - 1.f) * 2.f - 1.f, -1.1f), 1.1f);

        const float ix = (nx + 1.f) * 0.5f * (float)(WW - 1);
        const float iy = (ny + 1.f) * 0.5f * (float)(HH - 1);
        const float x0f = floorf(ix), y0f = floorf(iy);
        const float x1f = x0f + 1.f, y1f = y0f + 1.f;
        const float wx1 = ix - x0f, wx0 = 1.f - wx1;
        const float wy1 = iy - y0f, wy0 = 1.f - wy1;

        const float vx0 = (x0f >= 0.f && x0f < (float)WW) ? 1.f : 0.f;
        const float vx1 = (x1f >= 0.f && x1f < (float)WW) ? 1.f : 0.f;
        const float vy0 = (y0f >= 0.f && y0f < (float)HH) ? 1.f : 0.f;
        const float vy1 = (y1f >= 0.f && y1f < (float)HH) ? 1.f : 0.f;

        const float w00 = wx0 * wy0 * vx0 * vy0;
        const float w10 = wx1 * wy0 * vx1 * vy0;
        const float w01 = wx0 * wy1 * vx0 * vy1;
        const float w11 = wx1 * wy1 * vx1 * vy1;

        const int xi0 = min(max((int)x0f, 0), WW - 1);
        const int xi1 = min(max((int)x1f, 0), WW - 1);
        const int yi0 = min(max((int)y0f, 0), HH - 1);
        const int yi1 = min(max((int)y1f, 0), HH - 1);

        // pair base: slots {xb, xb+1}; remap corner weights onto slots
        // (handles x0f<0 -> both corners = px0, and x0f=W-1 -> both = px(W-1))
        const int xb = min(max((int)x0f, 0), WW - 2);
        const float s0 = (xi0 == xb ? w00 : 0.f) + (xi1 == xb ? w10 : 0.f);
        const float s1 = (xi0 == xb + 1 ? w00 : 0.f) + (xi1 == xb + 1 ? w10 : 0.f);
        const float t0 = (xi0 == xb ? w01 : 0.f) + (xi1 == xb ? w11 : 0.f);
        const float t1 = (xi0 == xb + 1 ? w01 : 0.f) + (xi1 == xb + 1 ? w11 : 0.f);

        const unsigned us0 = (unsigned)(s0 * 255.f + 0.5f);
        const unsigned us1 = (unsigned)(s1 * 255.f + 0.5f);
        const unsigned ut0 = (unsigned)(t0 * 255.f + 0.5f);
        const unsigned ut1 = (unsigned)(t1 * 255.f + 0.5f);
        unsigned wp = us0 | (us1 << 8) | (ut0 << 16) | (ut1 << 24);
        wpk[n] = inb ? wp : 0u;

        const unsigned char* img = tz + (size_t)pb * HW * 8;
        L0[n] = *(const uint4a*)(img + ((size_t)(yi0 * WW + xb)) * 8);
        L1[n] = *(const uint4a*)(img + ((size_t)(yi1 * WW + xb)) * 8);
    }

    // ---------------- stage 2: unpack + blend all cameras ------------------
    unsigned acc[16];
#pragma unroll
    for (int j = 0; j < 16; ++j) acc[j] = 0u;

    const unsigned M = 0x0F0F0F0Fu;

#pragma unroll
    for (int n = 0; n < NCAMS; ++n) {
        const unsigned wp = wpk[n];
        // q[0],q[1] = pixel xb (j0-7, j8-15); q[2],q[3] = pixel xb+1 — row y0
        const unsigned q[4] = {L0[n].x, L0[n].y, L0[n].z, L0[n].w};
        const unsigned r[4] = {L1[n].x, L1[n].y, L1[n].z, L1[n].w};
#pragma unroll
        for (int d = 0; d < 2; ++d) {
#pragma unroll
            for (int half = 0; half < 2; ++half) {
                // byte lane b of extracted dword = joint 8d + 2b + half
                const unsigned eA = half ? ((q[d]     >> 4) & M) : (q[d]     & M);
                const unsigned eB = half ? ((q[d + 2] >> 4) & M) : (q[d + 2] & M);
                const unsigned eC = half ? ((r[d]     >> 4) & M) : (r[d]     & M);
                const unsigned eD = half ? ((r[d + 2] >> 4) & M) : (r[d + 2] & M);
                const unsigned tABlo = prm(eA, eB, 0x01050004u); // {A0,B0,A1,B1}
                const unsigned tABhi = prm(eA, eB, 0x03070206u); // {A2,B2,A3,B3}
                const unsigned tCDlo = prm(eC, eD, 0x01050004u);
                const unsigned tCDhi = prm(eC, eD, 0x03070206u);
                const unsigned r0 = prm(tABlo, tCDlo, 0x01000504u); // {A,B,C,D} lane0
                const unsigned r1 = prm(tABlo, tCDlo, 0x03020706u);
                const unsigned r2 = prm(tABhi, tCDhi, 0x01000504u);
                const unsigned r3 = prm(tABhi, tCDhi, 0x03020706u);
                const int j0 = 8 * d + half;
                acc[j0 + 0] = dot4u8(r0, wp, acc[j0 + 0]);
                acc[j0 + 2] = dot4u8(r1, wp, acc[j0 + 2]);
                acc[j0 + 4] = dot4u8(r2, wp, acc[j0 + 4]);
                acc[j0 + 6] = dot4u8(r3, wp, acc[j0 + 6]);
            }
        }
    }

    const float inv = frcp((den + 1e-6f) * (15.f * 255.f));
    float* cout = out + (size_t)b * JJ * NBINS + m;
#pragma unroll
    for (int j = 0; j < JJ; ++j) {
        float v = (float)acc[j] * inv;
        v = fminf(fmaxf(v, 0.f), 1.f);
        __builtin_nontemporal_store(v, cout + (size_t)j * NBINS);
    }
}

// ---------------------------------------------------------------------------
// Fallback (R1 kernel): used only if ws_size < WS_NEEDED.
// ---------------------------------------------------------------------------
__global__ __launch_bounds__(BLOCK) void project_kernel_fb(
    const float* __restrict__ hm,
    const float* __restrict__ R, const float* __restrict__ T,
    const float* __restrict__ f, const float* __restrict__ c,
    const float* __restrict__ k, const float* __restrict__ p,
    const float* __restrict__ wh,
    const float* __restrict__ gc, const float* __restrict__ gs,
    float* __restrict__ out)
{
    const int b = blockIdx.x / BLOCKS_PER_B;
    const int m = (blockIdx.x % BLOCKS_PER_B) * BLOCK + threadIdx.x;
    const int i   = m / (CYY * CZZ);
    const int rem = m - i * (CYY * CZZ);
    const int jy  = rem / CZZ;
    const int kz  = rem - jy * CZZ;

    const float gs0 = gs[0], gs1 = gs[1], gs2 = gs[2];
    const float gx = -0.5f * gs0 + (float)i  * (gs0 / (float)(CXX - 1)) + gc[b * 3 + 0];
    const float gy = -0.5f * gs1 + (float)jy * (gs1 / (float)(CYY - 1)) + gc[b * 3 + 1];
    const float gz = -0.5f * gs2 + (float)kz * (gs2 / (float)(CZZ - 1)) + gc[b * 3 + 2];

    float* gout = out + CUBES_ELEMS + ((size_t)b * NBINS + m) * 3;
    gout[0] = gx; gout[1] = gy; gout[2] = gz;

    float num[JJ];
#pragma unroll
    for (int j = 0; j < JJ; ++j) num[j] = 0.f;
    float den = 0.f;

    for (int n = 0; n < NCAMS; ++n) {
        const int pb = n * BB + b;
        const float* Rp = R + pb * 9;
        const float dx = gx - T[pb * 3 + 0];
        const float dy = gy - T[pb * 3 + 1];
        const float dz = gz - T[pb * 3 + 2];
        const float xc = Rp[0] * dx + Rp[1] * dy + Rp[2] * dz;
        const float yc = Rp[3] * dx + Rp[4] * dy + Rp[5] * dz;
        const float zc = Rp[6] * dx + Rp[7] * dy + Rp[8] * dz;
        const float y0 = xc / zc;
        const float y1 = yc / zc;
        const float r2 = y0 * y0 + y1 * y1;
        const float k0 = k[pb * 3 + 0], k1 = k[pb * 3 + 1], k2 = k[pb * 3 + 2];
        const float radial = 1.f + k0 * r2 + k1 * r2 * r2 + k2 * r2 * r2 * r2;
        const float p0v = p[pb * 2 + 0], p1v = p[pb * 2 + 1];
        const float s = radial + p0v * y1 + p1v * y0;
        const float xy0 = y0 * s + r2 * p1v;
        const float xy1 = y1 * s + r2 * p0v;
        const float pixx = xy0 * f[pb * 2 + 0] + c[pb * 2 + 0];
        const float pixy = xy1 * f[pb * 2 + 1] + c[pb * 2 + 1];
        const float wv = wh[pb * 2 + 0], hv = wh[pb * 2 + 1];
        const bool inb = (pixx >= 0.f) & (pixy >= 0.f) & (pixx < wv) & (pixy < hv);
        if (!inb) continue;
        den += 1.f;
        const float maxwh = fmaxf(wv, hv);
        float pcx = fminf(fmaxf(pixx, -1.f), maxwh);
        float pcy = fminf(fmaxf(pixy, -1.f), maxwh);
        float nx = fminf(fmaxf(pcx / (wv - 1.f) * 2.f - 1.f, -1.1f), 1.1f);
        float ny = fminf(fmaxf(pcy / (hv - 1.f) * 2.f - 1.f, -1.1f), 1.1f);
        const float ix = (nx + 1.f) * 0.5f * (float)(WW - 1);
        const float iy = (ny + 1.f) * 0.5f * (float)(HH - 1);
        const float x0f = floorf(ix), y0f = floorf(iy);
        const float x1f = x0f + 1.f, y1f = y0f + 1.f;
        const float wx1 = ix - x0f, wx0 = 1.f - wx1;
        const float wy1 = iy - y0f, wy0 = 1.f - wy1;
        const float vx0 = (x0f >= 0.f && x0f < (float)WW) ? 1.f : 0.f;
        const float vx1 = (x1f >= 0.f && x1f < (float)WW) ? 1.f : 0.f;
        const float vy0 = (y0f >= 0.f && y0f < (float)HH) ? 1.f : 0.f;
        const float vy1 = (y1f >= 0.f && y1f < (float)HH) ? 1.f : 0.f;
        const float w00 = wx0 * wy0 * vx0 * vy0;
        const float w10 = wx1 * wy0 * vx1 * vy0;
        const float w01 = wx0 * wy1 * vx0 * vy1;
        const float w11 = wx1 * wy1 * vx1 * vy1;
        const int xi0 = min(max((int)x0f, 0), WW - 1);
        const int xi1 = min(max((int)x1f, 0), WW - 1);
        const int yi0 = min(max((int)y0f, 0), HH - 1);
        const int yi1 = min(max((int)y1f, 0), HH - 1);
        const int o00 = yi0 * WW + xi0;
        const int o10 = yi0 * WW + xi1;
        const int o01 = yi1 * WW + xi0;
        const int o11 = yi1 * WW + xi1;
        const float* img = hm + (size_t)pb * JJ * HW;
#pragma unroll
        for (int j = 0; j < JJ; ++j) {
            const float* pj = img + j * HW;
            num[j] += pj[o00] * w00 + pj[o10] * w10 + pj[o01] * w01 + pj[o11] * w11;
        }
    }

    const float inv = 1.f / (den + 1e-6f);
    float* cout = out + (size_t)b * JJ * NBINS + m;
#pragma unroll
    for (int j = 0; j < JJ; ++j) {
        float v = num[j] * inv;
        v = (v != v) ? 0.f : v;
        v = fminf(fmaxf(v, 0.f), 1.f);
        cout[(size_t)j * NBINS] = v;
    }
}

extern "C" void kernel_launch(void* const* d_in, const int* in_sizes, int n_in,
                              void* d_out, int out_size, void* d_ws, size_t ws_size,
                              hipStream_t stream) {
    const float* hm = (const float*)d_in[0];
    const float* R  = (const float*)d_in[1];
    const float* T  = (const float*)d_in[2];
    const float* f  = (const float*)d_in[3];
    const float* c  = (const float*)d_in[4];
    const float* k  = (const float*)d_in[5];
    const float* p  = (const float*)d_in[6];
    const float* wh = (const float*)d_in[7];
    const float* gc = (const float*)d_in[8];
    const float* gs = (const float*)d_in[9];
    float* out = (float*)d_out;

    if (ws_size >= WS_NEEDED + 16) {   // +16: pair-load may touch 8B past last pixel
        uint2* tz = (uint2*)d_ws;
        transpose_kernel_u4<<<dim3(NCAMS * BB * HW / BLOCK), dim3(BLOCK), 0, stream>>>(
            hm, tz);
        project_kernel_u4<<<dim3(GRID), dim3(BLOCK), 0, stream>>>(
            (const unsigned char*)tz, R, T, f, c, k, p, wh, gc, gs, out);
    } else {
        project_kernel_fb<<<dim3(GRID), dim3(BLOCK), 0, stream>>>(
            hm, R, T, f, c, k, p, wh, gc, gs, out);
    }
}